// Round 2
// baseline (11806.822 us; speedup 1.0000x reference)
//
#include <hip/hip_runtime.h>

// LSTM on MI355X — persistent-kernel version.
// One kernel runs all 512 timesteps: W hi/lo lives in LDS for the whole run,
// c-state lives in VGPRs, steps separated by a device-scope atomic grid barrier.
// Numerics identical to R0 (split-bf16 hi/lo MFMA, pseudo-fp32).

namespace {
constexpr int T_STEPS = 512;
constexpr int BATCH   = 64;
constexpr int DI      = 512;
constexpr int DL      = 1024;
constexpr int NKC     = 48;   // K=1536 in chunks of 32
constexpr int NKC_H   = 32;   // h-part chunks (K=1024)
constexpr int NBLK    = 256;  // grid size == CU count (residency for barrier)
}

typedef __attribute__((ext_vector_type(8))) short bf16x8;
typedef __attribute__((ext_vector_type(8))) unsigned short u16x8;
typedef __attribute__((ext_vector_type(4))) float f32x4;

__device__ __forceinline__ unsigned short f2bf(float x){
  unsigned int u = __float_as_uint(x);
  return (unsigned short)((u + 0x7FFFu + ((u >> 16) & 1u)) >> 16);
}
__device__ __forceinline__ float bf2f(unsigned short b){
  return __uint_as_float(((unsigned int)b) << 16);
}

// ---------------- prep: embeddings -> bf16 [T*B][DI] ----------------
__global__ void prep_xe(const int* __restrict__ X, const float* __restrict__ emb,
                        unsigned short* __restrict__ xe){
  int i = blockIdx.x * blockDim.x + threadIdx.x;      // one thread per 8 elems
  const int total = T_STEPS * BATCH * DI / 8;
  if (i >= total) return;
  int row = i >> 6;            // DI/8 = 64 segments per row; row = t*64+b
  int seg = i & 63;
  int tok = X[row];
  const float* src = emb + (long long)tok * DI + seg * 8;
  float4 v0 = *(const float4*)src;
  float4 v1 = *(const float4*)(src + 4);
  u16x8 o;
  o[0]=f2bf(v0.x); o[1]=f2bf(v0.y); o[2]=f2bf(v0.z); o[3]=f2bf(v0.w);
  o[4]=f2bf(v1.x); o[5]=f2bf(v1.y); o[6]=f2bf(v1.z); o[7]=f2bf(v1.w);
  *(u16x8*)(xe + (long long)row * DI + seg * 8) = o;
}

// ---------------- prep: pack W into MFMA B-fragment layout, hi/lo ----------------
__global__ void prep_w(const float* __restrict__ Wf, const float* __restrict__ Wi,
                       const float* __restrict__ Wc, const float* __restrict__ Wo,
                       unsigned short* __restrict__ W_hi, unsigned short* __restrict__ W_lo){
  int idx = blockIdx.x * blockDim.x + threadIdx.x;
  if (idx >= 256 * NKC * 64) return;
  int lane = idx & 63;
  int kc   = (idx >> 6) % NKC;
  int bk   = idx / (64 * NKC);
  int lc = lane & 15, kg = lane >> 4;
  int g  = lc >> 2;
  int jl = bk * 4 + (lc & 3);
  const float* Wg = (g == 0) ? Wf : ((g == 1) ? Wi : ((g == 2) ? Wc : Wo));
  int kbase = kc * 32 + kg * 8;
  u16x8 hi, lo;
#pragma unroll
  for (int j = 0; j < 8; j++){
    float wv = Wg[(long long)(kbase + j) * DL + jl];
    unsigned short h = f2bf(wv);
    hi[j] = h;
    lo[j] = f2bf(wv - bf2f(h));
  }
  *(u16x8*)(W_hi + ((long long)(bk * NKC + kc) * 64 + lane) * 8) = hi;
  if (kc < NKC_H)
    *(u16x8*)(W_lo + ((long long)(bk * NKC_H + kc) * 64 + lane) * 8) = lo;
}

// ---------------- prep: h0 -> hi/lo planes, bias pack, barrier reset ----------------
__global__ void prep_h(const float* __restrict__ h0,
                       const float* __restrict__ bf_, const float* __restrict__ bi_,
                       const float* __restrict__ bc_, const float* __restrict__ bo_,
                       unsigned short* __restrict__ h_hi, unsigned short* __restrict__ h_lo,
                       float* __restrict__ bias_pack, unsigned int* __restrict__ bar){
  int i = blockIdx.x * blockDim.x + threadIdx.x;
  if (i < BATCH * DL){
    float v = h0[i];
    unsigned short hb = f2bf(v);
    h_hi[i] = hb;
    h_lo[i] = f2bf(v - bf2f(hb));
  }
  if (i < 4096){
    int r = i & 3, g = (i >> 2) & 3, bk = i >> 4;
    const float* bg = (g == 0) ? bf_ : ((g == 1) ? bi_ : ((g == 2) ? bc_ : bo_));
    bias_pack[i] = bg[bk * 4 + r];
  }
  if (i == 0) bar[0] = 0u;
}

// ---------------- persistent LSTM: all 512 steps in one kernel ----------------
// 256 blocks x 256 threads; block bk owns 4 latent cols x 4 gates = 16 gate-cols.
// W (80 KB) stays in LDS across all steps; c-state in VGPRs; grid barrier per step.
__launch_bounds__(256, 1)
__global__ void lstm_persist(const unsigned short* __restrict__ xe,
                             const unsigned short* __restrict__ W_hi,
                             const unsigned short* __restrict__ W_lo,
                             unsigned short* __restrict__ h_hi,   // [2][B*DL]
                             unsigned short* __restrict__ h_lo,   // [2][B*DL]
                             const float* __restrict__ bias_pack,
                             float* __restrict__ out,
                             unsigned int* __restrict__ bar){
  extern __shared__ unsigned short lds[];
  unsigned short* lds_hi = lds;              // NKC  *512 = 24576 elems (48 KB)
  unsigned short* lds_lo = lds + NKC * 512;  // NKC_H*512 = 16384 elems (32 KB)
  const int tid  = threadIdx.x;
  const int bk   = blockIdx.x;
  const int w    = tid >> 6;
  const int lane = tid & 63;

  // stage W once for the whole run
  const uint4* srcHi = (const uint4*)(W_hi + (size_t)bk * NKC * 512);
  uint4* dHi = (uint4*)lds_hi;
  for (int i = tid; i < 3072; i += 256) dHi[i] = srcHi[i];
  const uint4* srcLo = (const uint4*)(W_lo + (size_t)bk * NKC_H * 512);
  uint4* dLo = (uint4*)lds_lo;
  for (int i = tid; i < 2048; i += 256) dLo[i] = srcLo[i];
  __syncthreads();

  const int lc = lane & 15;
  const int kg = lane >> 4;
  const int g  = lc >> 2;
  const int rowb = (w << 4) + lc;            // A-frag batch row
  const float bias = bias_pack[bk * 16 + lc];
  const int srcBase = (lane & 48) | (lc & 3);
  const int hOff = rowb * DL + kg * 8;
  const int xOff = rowb * DI + kg * 8;
  float cr0 = 0.f, cr1 = 0.f, cr2 = 0.f, cr3 = 0.f;   // c-state (g==0 lanes)

#pragma unroll 1
  for (int t = 0; t < T_STEPS; ++t){
    const int rb = t & 1;
    const unsigned short* hRowHi = h_hi + rb * (BATCH * DL) + hOff;
    const unsigned short* hRowLo = h_lo + rb * (BATCH * DL) + hOff;
    const unsigned short* xRow   = xe + (size_t)t * BATCH * DI + xOff;
    unsigned short* hWHi = h_hi + (rb ^ 1) * (BATCH * DL);
    unsigned short* hWLo = h_lo + (rb ^ 1) * (BATCH * DL);
    float* out_t = out + (size_t)t * BATCH * DL;

    f32x4 acc0 = {0.f,0.f,0.f,0.f}, acc1 = {0.f,0.f,0.f,0.f};
    // h-part: 3-term split-bf16, two independent accumulator chains
#pragma unroll 4
    for (int kc = 0; kc < NKC_H; kc += 2){
      bf16x8 ah0 = *(const bf16x8*)(hRowHi + kc * 32);
      bf16x8 al0 = *(const bf16x8*)(hRowLo + kc * 32);
      bf16x8 bh0 = *(const bf16x8*)(lds_hi + kc * 512 + lane * 8);
      bf16x8 bl0 = *(const bf16x8*)(lds_lo + kc * 512 + lane * 8);
      acc0 = __builtin_amdgcn_mfma_f32_16x16x32_bf16(ah0, bh0, acc0, 0, 0, 0);
      acc0 = __builtin_amdgcn_mfma_f32_16x16x32_bf16(ah0, bl0, acc0, 0, 0, 0);
      acc0 = __builtin_amdgcn_mfma_f32_16x16x32_bf16(al0, bh0, acc0, 0, 0, 0);
      bf16x8 ah1 = *(const bf16x8*)(hRowHi + (kc + 1) * 32);
      bf16x8 al1 = *(const bf16x8*)(hRowLo + (kc + 1) * 32);
      bf16x8 bh1 = *(const bf16x8*)(lds_hi + (kc + 1) * 512 + lane * 8);
      bf16x8 bl1 = *(const bf16x8*)(lds_lo + (kc + 1) * 512 + lane * 8);
      acc1 = __builtin_amdgcn_mfma_f32_16x16x32_bf16(ah1, bh1, acc1, 0, 0, 0);
      acc1 = __builtin_amdgcn_mfma_f32_16x16x32_bf16(ah1, bl1, acc1, 0, 0, 0);
      acc1 = __builtin_amdgcn_mfma_f32_16x16x32_bf16(al1, bh1, acc1, 0, 0, 0);
    }
    // x-part: single bf16 term
#pragma unroll 4
    for (int kc = 0; kc < 16; kc += 2){
      bf16x8 ax0 = *(const bf16x8*)(xRow + kc * 32);
      bf16x8 bh0 = *(const bf16x8*)(lds_hi + (NKC_H + kc) * 512 + lane * 8);
      acc0 = __builtin_amdgcn_mfma_f32_16x16x32_bf16(ax0, bh0, acc0, 0, 0, 0);
      bf16x8 ax1 = *(const bf16x8*)(xRow + (kc + 1) * 32);
      bf16x8 bh1 = *(const bf16x8*)(lds_hi + (NKC_H + kc + 1) * 512 + lane * 8);
      acc1 = __builtin_amdgcn_mfma_f32_16x16x32_bf16(ax1, bh1, acc1, 0, 0, 0);
    }
    f32x4 acc = acc0 + acc1;

    // epilogue: D[row=(lane>>4)*4+r][col=lane&15]; gather f/i/c/o via shfl
    float creg[4] = {cr0, cr1, cr2, cr3};
#pragma unroll
    for (int r = 0; r < 4; r++){
      float v = acc[r] + bias;
      float vF = __shfl(v, srcBase);
      float vI = __shfl(v, srcBase + 4);
      float vC = __shfl(v, srcBase + 8);
      float vO = __shfl(v, srcBase + 12);
      if (g == 0){
        int b = (w << 4) | (kg << 2) | r;
        int j = (bk << 2) | (lc & 3);
        float ft = 1.f / (1.f + __expf(-vF));
        float it = 1.f / (1.f + __expf(-vI));
        float gt = tanhf(vC);
        float ot = 1.f / (1.f + __expf(-vO));
        float cn = ft * creg[r] + it * gt;
        creg[r] = cn;
        float hn = ot * tanhf(cn);
        int ci = b * DL + j;
        out_t[ci] = hn;
        unsigned short hb = f2bf(hn);
        hWHi[ci] = hb;
        hWLo[ci] = f2bf(hn - bf2f(hb));
      }
    }
    cr0 = creg[0]; cr1 = creg[1]; cr2 = creg[2]; cr3 = creg[3];

    // grid barrier: release my writes, wait for all 256 blocks
    __syncthreads();
    if (tid == 0){
      __hip_atomic_fetch_add(bar, 1u, __ATOMIC_RELEASE, __HIP_MEMORY_SCOPE_AGENT);
      const unsigned tgt = (unsigned)NBLK * (unsigned)(t + 1);
      int spin = 0;
      while (__hip_atomic_load(bar, __ATOMIC_ACQUIRE, __HIP_MEMORY_SCOPE_AGENT) < tgt){
        __builtin_amdgcn_s_sleep(1);
        if (++spin > (1 << 21)) break;   // bailout: fail loud (absmax) not hang
      }
    }
    __syncthreads();
  }
}

extern "C" void kernel_launch(void* const* d_in, const int* in_sizes, int n_in,
                              void* d_out, int out_size, void* d_ws, size_t ws_size,
                              hipStream_t stream){
  const int*   X   = (const int*)d_in[0];
  const float* h0  = (const float*)d_in[1];
  const float* emb = (const float*)d_in[2];
  const float* Wf  = (const float*)d_in[3];
  const float* bf_ = (const float*)d_in[4];
  const float* Wi  = (const float*)d_in[5];
  const float* bi_ = (const float*)d_in[6];
  const float* Wc  = (const float*)d_in[7];
  const float* bc_ = (const float*)d_in[8];
  const float* Wo  = (const float*)d_in[9];
  const float* bo_ = (const float*)d_in[10];
  float* out = (float*)d_out;

  char* ws = (char*)d_ws;
  size_t off = 0;
  auto alloc = [&](size_t bytes) -> void* {
    void* p = ws + off;
    off = (off + bytes + 255) & ~((size_t)255);
    return p;
  };
  unsigned short* xe        = (unsigned short*)alloc(sizeof(unsigned short) * (size_t)T_STEPS * BATCH * DI);
  unsigned short* W_hi      = (unsigned short*)alloc(sizeof(unsigned short) * (size_t)256 * NKC * 512);
  unsigned short* W_lo      = (unsigned short*)alloc(sizeof(unsigned short) * (size_t)256 * NKC_H * 512);
  unsigned short* h_hi      = (unsigned short*)alloc(sizeof(unsigned short) * 2 * BATCH * DL);
  unsigned short* h_lo      = (unsigned short*)alloc(sizeof(unsigned short) * 2 * BATCH * DL);
  float*          bias_pack = (float*)alloc(sizeof(float) * 4096);
  unsigned int*   bar       = (unsigned int*)alloc(sizeof(unsigned int) * 64);
  (void)ws_size; (void)in_sizes; (void)n_in; (void)out_size;

  // allow 80 KB dynamic LDS (defensive; HIP may not need the opt-in)
  static bool attr_set = false;
  if (!attr_set){
    hipFuncSetAttribute((const void*)lstm_persist,
                        hipFuncAttributeMaxDynamicSharedMemorySize, 160 * 1024);
    attr_set = true;
  }

  hipLaunchKernelGGL(prep_xe, dim3(8192), dim3(256), 0, stream, X, emb, xe);
  hipLaunchKernelGGL(prep_w,  dim3(3072), dim3(256), 0, stream, Wf, Wi, Wc, Wo, W_hi, W_lo);
  hipLaunchKernelGGL(prep_h,  dim3(256),  dim3(256), 0, stream, h0, bf_, bi_, bc_, bo_,
                     h_hi, h_lo, bias_pack, bar);
  hipLaunchKernelGGL(lstm_persist, dim3(NBLK), dim3(256), 80 * 1024, stream,
                     xe, W_hi, W_lo, h_hi, h_lo, bias_pack, out, bar);
}